// Round 1
// baseline (125.246 us; speedup 1.0000x reference)
//
#include <hip/hip_runtime.h>

#define N_ROWS 32768
#define DIM    256
#define KCODES 2048
#define CSCALE 4096.0f

typedef __attribute__((ext_vector_type(16))) float f32x16;
typedef __attribute__((ext_vector_type(4)))  unsigned int u32x4;

union frag16 { u32x4 v; long l[2]; };

// explicit waits: all volatile asm so mutual program order is preserved
#define SWAIT(s) asm volatile("s_waitcnt " s)

__device__ __forceinline__ void gl16(const void* g, void* l) {
    __builtin_amdgcn_global_load_lds(
        (const __attribute__((address_space(1))) unsigned int*)g,
        (__attribute__((address_space(3))) unsigned int*)l, 16, 0, 0);
}

// inline-asm LDS read: invisible to the compiler's waitcnt insertion, so the
// global_load_lds -> ds_read dependency is governed ONLY by our counted waits.
__device__ __forceinline__ u32x4 ldsr128(const void* p) {
    const unsigned a =
        (unsigned)(unsigned long long)(__attribute__((address_space(3))) const char*)p;
    u32x4 d;
    asm volatile("ds_read_b128 %0, %1" : "=&v"(d) : "v"(a));
    return d;
}

// pack 16 fp32 -> 16 fp8 e4m3 (4 dwords)
__device__ __forceinline__ uint4 pack16(const float* s) {
    int a = __builtin_amdgcn_cvt_pk_fp8_f32(s[0],  s[1],  0, false);
    a     = __builtin_amdgcn_cvt_pk_fp8_f32(s[2],  s[3],  a, true);
    int b = __builtin_amdgcn_cvt_pk_fp8_f32(s[4],  s[5],  0, false);
    b     = __builtin_amdgcn_cvt_pk_fp8_f32(s[6],  s[7],  b, true);
    int c = __builtin_amdgcn_cvt_pk_fp8_f32(s[8],  s[9],  0, false);
    c     = __builtin_amdgcn_cvt_pk_fp8_f32(s[10], s[11], c, true);
    int d = __builtin_amdgcn_cvt_pk_fp8_f32(s[12], s[13], 0, false);
    d     = __builtin_amdgcn_cvt_pk_fp8_f32(s[14], s[15], d, true);
    uint4 o; o.x = a; o.y = b; o.z = c; o.w = d;
    return o;
}

// Piece layout: within each 64B k-chunk, piece d (=h*2+q, 16B) holds the two 8B
// MFMA fragments (ks=2q, ks=2q+1) for k-half h.

// ---------------- prologue: cb -> fp8 (x4096) in piece layout + halfcn ----------
__global__ void prep_cb(const float* __restrict__ cb, unsigned int* __restrict__ cbf8,
                        float* __restrict__ halfcn, float* __restrict__ loss) {
    const int t    = threadIdx.x;            // 256 thr = 4 codes x 64 dword slots
    const int code = blockIdx.x * 4 + (t >> 6);
    const int s    = t & 63;                 // output dword slot
    if (blockIdx.x == 0 && t == 0) *loss = 0.0f;
    const int kc = s >> 4, d = (s >> 2) & 3, b4 = (s & 3) * 4;
    const int h = d >> 1, q = d & 1;
    const int k0 = kc * 64 + q * 32 + (b4 >> 3) * 16 + h * 8 + (b4 & 7);
    float4 v = *(const float4*)&cb[(size_t)code * DIM + k0];
    int pk = __builtin_amdgcn_cvt_pk_fp8_f32(v.x * CSCALE, v.y * CSCALE, 0, false);
    pk     = __builtin_amdgcn_cvt_pk_fp8_f32(v.z * CSCALE, v.w * CSCALE, pk, true);
    cbf8[(size_t)code * 64 + s] = (unsigned int)pk;
    float ssum = v.x * v.x + v.y * v.y + v.z * v.z + v.w * v.w;
    #pragma unroll
    for (int o = 32; o > 0; o >>= 1) ssum += __shfl_down(ssum, o, 64);
    if (s == 0) halfcn[code] = 0.5f * CSCALE * ssum;
}

// ---------------- fused: argmin over all 2048 codes + gather + loss -------------
// Barrier-free K-loop. A fragments fully register-resident (identical across all
// passes). B wave-private ring-3 in LDS via global_load_lds, consumed through
// inline-asm ds_read_b128 so ONLY the counted vmcnt/lgkmcnt waits gate them
// (stage(i+3) issued at step i => the vmcnt(8) wait sees 3-step-old loads).
__global__ __launch_bounds__(256, 2) void vq_fused(
        const float* __restrict__ x, const float* __restrict__ cb,
        const char* __restrict__ cbf8, const float* __restrict__ halfcn,
        float* __restrict__ out, float* __restrict__ loss) {
    __shared__ char As[4][4096];      // [kc][64 rows x 64B], 16B-granule XOR swizzle
    __shared__ char Bs[3][4][4096];   // [ring3][wave][64 codes x 64B], swizzled
    __shared__ float hcs[KCODES];     // per-code bias (0.5*CSCALE*||c||^2)
    __shared__ float red[64][4];
    __shared__ int  idxs[64];
    __shared__ float lred[4];

    const int t    = threadIdx.x;
    const int lane = t & 63;
    const int w    = t >> 6;
    const int l32  = lane & 31;
    const int h    = lane >> 5;
    const int row0 = blockIdx.x * 64;

    // ---- stage A once: fp32 -> fp8 e4m3 pieces, swizzled LDS; bias -> LDS ----
    {
        const int r   = t >> 2;
        const int kc  = t & 3;
        const int key = (r >> 1) & 3;
        const float* src = x + (size_t)(row0 + r) * DIM + kc * 64;
        float buf[16];
        #pragma unroll
        for (int p = 0; p < 4; p++) {
            const int d = p ^ key, hh = d >> 1, qq = d & 1;
            #pragma unroll
            for (int j = 0; j < 4; j++) *(float4*)(buf + j * 4) =
                *(const float4*)(src + qq * 32 + (j >> 1) * 16 + hh * 8 + (j & 1) * 4);
            *(uint4*)(As[kc] + r * 64 + p * 16) = pack16(buf);
        }
        #pragma unroll
        for (int j = 0; j < 8; j++) hcs[j * 256 + t] = halfcn[j * 256 + t];
    }

    // ---- wave-private B staging (ring-3) ----
    const int lsub = lane >> 2;
    const int lpos = lane & 3;
    auto stageB = [&](int j) {
        const int pass_ = j >> 2, kc_ = j & 3;
        char* dst = Bs[j % 3][w];
        #pragma unroll
        for (int r_ = 0; r_ < 4; r_++) {
            const int lc = r_ * 16 + lsub;
            const int g  = lpos ^ ((lc >> 1) & 3);
            const char* src = cbf8 + (size_t)(pass_ * 256 + w * 64 + lc) * 256
                              + kc_ * 64 + g * 16;
            gl16(src, dst + r_ * 1024);
        }
    };

    const int key = (l32 >> 1) & 3;
    const int p0  = (h * 2 + 0) ^ key;
    const int p1  = (h * 2 + 1) ^ key;

    frag16 afr[4][2][2];   // resident A fragments: [kc][rt][q], 64 VGPRs
    frag16 bf[2][2][2];    // B double-buffer: [set][ct][q]

    float mp[2][16];
    #pragma unroll
    for (int rt = 0; rt < 2; rt++)
        #pragma unroll
        for (int r = 0; r < 16; r++) mp[rt][r] = -3.0e38f;

    __syncthreads();                  // A + hcs visible to all waves

    // resident A fragments (plain C++ reads: compiler tracks stage-A dependency)
    #pragma unroll
    for (int kc = 0; kc < 4; kc++) {
        const char* ab = As[kc];
        #pragma unroll
        for (int rt = 0; rt < 2; rt++) {
            const int rbase = (rt * 32 + l32) * 64;
            afr[kc][rt][0].v = *(const u32x4*)(ab + rbase + p0 * 16);
            afr[kc][rt][1].v = *(const u32x4*)(ab + rbase + p1 * 16);
        }
    }

    stageB(0); stageB(1); stageB(2);   // 12 loads in flight
    SWAIT("vmcnt(8)");                 // stage(0) complete
    {
        const char* bb = Bs[0][w];
        #pragma unroll
        for (int ct = 0; ct < 2; ct++) {
            const int cbase = (ct * 32 + l32) * 64;
            bf[0][ct][0].v = ldsr128(bb + cbase + p0 * 16);
            bf[0][ct][1].v = ldsr128(bb + cbase + p1 * 16);
        }
    }

    #pragma unroll
    for (int pass = 0; pass < 8; ++pass) {
        const float hc0 = hcs[pass * 256 + w * 64 + l32];
        const float hc1 = hcs[pass * 256 + w * 64 + 32 + l32];
        f32x16 acc[2][2];
        #pragma unroll
        for (int rt = 0; rt < 2; rt++)
            #pragma unroll
            for (int r = 0; r < 16; r++) {
                acc[rt][0][r] = -hc0;
                acc[rt][1][r] = -hc1;
            }

        #pragma unroll
        for (int kc = 0; kc < 4; ++kc) {
            const int i  = pass * 4 + kc;
            const int cs = kc & 1;           // current B frag set (literal)
            const int ns = cs ^ 1;           // next B frag set

            // bf(i) landed; Bs[i%3] reads (issued at i-1) retired -> slot reusable
            SWAIT("lgkmcnt(0)");
            __builtin_amdgcn_sched_barrier(0);   // rule #18: no MFMA hoisting past the wait

            if (i + 3 < 32) {
                stageB(i + 3);               // writes slot i%3 (reads drained above)
                SWAIT("vmcnt(8)");           // stage(i+1) complete (issued 3 steps ago)
            } else if (i == 29) {
                SWAIT("vmcnt(4)");           // stage(30) complete
            } else if (i == 30) {
                SWAIT("vmcnt(0)");           // stage(31) complete
            }

            if (i + 1 < 32) {
                // issue asm ds_reads for step i+1 BEFORE this step's MFMAs
                const char* bb = Bs[(i + 1) % 3][w];
                #pragma unroll
                for (int ct = 0; ct < 2; ct++) {
                    const int cbase = (ct * 32 + l32) * 64;
                    bf[ns][ct][0].v = ldsr128(bb + cbase + p0 * 16);
                    bf[ns][ct][1].v = ldsr128(bb + cbase + p1 * 16);
                }
            }

            // MFMAs for step i: A resident, B set cs already resident - no wait
            __builtin_amdgcn_s_setprio(1);
            #pragma unroll
            for (int q = 0; q < 2; q++)
                #pragma unroll
                for (int hf = 0; hf < 2; hf++)
                    #pragma unroll
                    for (int rt = 0; rt < 2; rt++)
                        #pragma unroll
                        for (int ct = 0; ct < 2; ct++)
                            acc[rt][ct] = __builtin_amdgcn_mfma_f32_32x32x16_fp8_fp8(
                                afr[kc][rt][q].l[hf], bf[cs][ct][q].l[hf],
                                acc[rt][ct], 0, 0, 0);
            __builtin_amdgcn_s_setprio(0);
        }

        // fold pass into running max (pack 11-bit code id into low mantissa bits)
        #pragma unroll
        for (int ct = 0; ct < 2; ct++) {
            const unsigned code = (unsigned)(pass * 256 + w * 64 + ct * 32 + l32);
            #pragma unroll
            for (int rt = 0; rt < 2; rt++)
                #pragma unroll
                for (int r = 0; r < 16; r++) {
                    unsigned u = (__float_as_uint(acc[rt][ct][r]) & 0xFFFFF800u) | code;
                    mp[rt][r] = fmaxf(mp[rt][r], __uint_as_float(u));
                }
        }
    }

    // ---- cross-lane argmax over the 32 lanes sharing each output row ----
    #pragma unroll
    for (int m = 1; m <= 16; m <<= 1)
        #pragma unroll
        for (int rt = 0; rt < 2; rt++)
            #pragma unroll
            for (int r = 0; r < 16; r++)
                mp[rt][r] = fmaxf(mp[rt][r], __shfl_xor(mp[rt][r], m, 64));

    if (l32 == 0) {
        #pragma unroll
        for (int rt = 0; rt < 2; rt++)
            #pragma unroll
            for (int r = 0; r < 16; r++) {
                const int row = rt * 32 + (r & 3) + 8 * (r >> 2) + 4 * h;
                red[row][w] = mp[rt][r];
            }
    }
    __syncthreads();
    if (t < 64) {
        float b0 = fmaxf(fmaxf(red[t][0], red[t][1]), fmaxf(red[t][2], red[t][3]));
        idxs[t] = (int)(__float_as_uint(b0) & 2047u);
    }
    __syncthreads();

    // ---- fused gather (fp32 codebook) + loss partial ----
    float lsum = 0.0f;
    #pragma unroll 4
    for (int r = 0; r < 64; r++) {
        const int code = idxs[r];
        const float c  = cb[(size_t)code * DIM + t];
        const float xv = x[(size_t)(row0 + r) * DIM + t];
        out[(size_t)(row0 + r) * DIM + t] = c;
        const float d = xv - c;
        lsum += d * d;
    }
    #pragma unroll
    for (int o = 32; o > 0; o >>= 1) lsum += __shfl_down(lsum, o, 64);
    if (lane == 0) lred[w] = lsum;
    __syncthreads();
    if (t == 0) {
        const float scale = 1.25f / (float)((size_t)N_ROWS * DIM);  // (beta+1)/(N*D)
        atomicAdd(loss, (lred[0] + lred[1] + lred[2] + lred[3]) * scale);
    }
}

extern "C" void kernel_launch(void* const* d_in, const int* in_sizes, int n_in,
                              void* d_out, int out_size, void* d_ws, size_t ws_size,
                              hipStream_t stream) {
    const float* x  = (const float*)d_in[0];
    const float* cb = (const float*)d_in[1];
    float* out  = (float*)d_out;
    float* loss = out + (size_t)N_ROWS * DIM;

    char* ws = (char*)d_ws;
    unsigned int* cbf8 = (unsigned int*)ws;                        // 512 KB
    float* halfcn = (float*)(ws + (size_t)KCODES * 256);           // 8 KB

    prep_cb<<<KCODES / 4, 256, 0, stream>>>(cb, cbf8, halfcn, loss);
    vq_fused<<<N_ROWS / 64, 256, 0, stream>>>(x, cb, (const char*)cbf8, halfcn, out, loss);
}